// Round 14
// baseline (70.198 us; speedup 1.0000x reference)
//
#include <hip/hip_runtime.h>

#define BINS 256
#define BC_N 24   // B*C = 8*3
#define C_N  3
#define NROWS 12  // the row_sel = b*c bug uses only rows {0..8,10,12,14}
#define CH   85   // hist blocks per (row,img): 85*12*2 = 2040 = ~8/CU
#define ACH  128  // apply chunks

// ---------------------------------------------------------------------------
// Kernel 1: 256-bin histograms for the 12 USED rows of dst and ref.
// grid = (CH, 12 compact rows, 2 images), block = 256 (4 waves), 4 KB LDS.
//
// Hardware model (r2-r13, stable): two independent counting pipes per CU --
//   LDS atomic unit: strict ~57 cyc/ds_add wave-instr server = 1.12 lane-ops
//     /cyc/CU; saturated by feeders that CAMP on its queue (even 8/CU).
//   ballot bit-slicing on VALU: 0.79 px/cyc/CU measured at 24 waves/CU (r6).
// Config: per block, wave 0 = atomic feeder (3-deep batched loads; stays
// ahead of the 684-cyc atomic drain per 12-px batch), waves 1-3 = ballot.
// 8 blocks/CU -> 8 feeders + 24 ballot waves = both pipes at measured rates.
// Pixel split 59:41 = 1.12:0.79 balances completion. Ballot segment is an
// exact multiple of 64 float4 (all lanes valid -> no mask correction).
// bin = floor(x*256) == trunc for x in [0,1); min-clamp for the 1.0 edge.
// ---------------------------------------------------------------------------
__global__ __launch_bounds__(256) void hm_hist(const float* __restrict__ dst,
                                               const float* __restrict__ refp,
                                               unsigned int* __restrict__ part,
                                               int n4_per_row) {
    __shared__ unsigned int shist[BINS];      // atomic-pipe counts
    __shared__ unsigned int wsum[3][BINS];    // ballot-pipe counts

    const int t = threadIdx.x;
    const int l = t & 63;
    const int w = t >> 6;                     // 0..3

    shist[t] = 0u;
    __syncthreads();

    const int y = blockIdx.y;
    const int row = (y < 9) ? y : 2 * y - 8;  // {0..8,10,12,14}
    const float* img = blockIdx.z ? refp : dst;
    const float4* p = reinterpret_cast<const float4*>(img) + (size_t)row * n4_per_row;

    const int span = (n4_per_row + CH - 1) / CH;         // 3085
    const int lo = blockIdx.x * span;
    const int hi = min(lo + span, n4_per_row);
    const int n  = hi - lo;
    const int SB = ((n * 41) / 100) & ~63;    // ballot segment, multiple of 64
    const int mid = hi - SB;                  // [lo,mid) atomic, [mid,hi) ballot

    if (w == 0) {
        // ----- atomic feeder wave: 3-deep batched loads, fire-and-forget -----
        int base = lo;
        for (; base + 192 <= mid; base += 192) {
            float4 v0 = p[base + l];
            float4 v1 = p[base + 64 + l];
            float4 v2 = p[base + 128 + l];
            __builtin_amdgcn_sched_barrier(0);
            atomicAdd(&shist[min((int)(v0.x * 256.0f), 255)], 1u);
            atomicAdd(&shist[min((int)(v0.y * 256.0f), 255)], 1u);
            atomicAdd(&shist[min((int)(v0.z * 256.0f), 255)], 1u);
            atomicAdd(&shist[min((int)(v0.w * 256.0f), 255)], 1u);
            atomicAdd(&shist[min((int)(v1.x * 256.0f), 255)], 1u);
            atomicAdd(&shist[min((int)(v1.y * 256.0f), 255)], 1u);
            atomicAdd(&shist[min((int)(v1.z * 256.0f), 255)], 1u);
            atomicAdd(&shist[min((int)(v1.w * 256.0f), 255)], 1u);
            atomicAdd(&shist[min((int)(v2.x * 256.0f), 255)], 1u);
            atomicAdd(&shist[min((int)(v2.y * 256.0f), 255)], 1u);
            atomicAdd(&shist[min((int)(v2.z * 256.0f), 255)], 1u);
            atomicAdd(&shist[min((int)(v2.w * 256.0f), 255)], 1u);
        }
        for (int i = base + l; i < mid; i += 64) {   // masked tail
            float4 v = p[i];
            atomicAdd(&shist[min((int)(v.x * 256.0f), 255)], 1u);
            atomicAdd(&shist[min((int)(v.y * 256.0f), 255)], 1u);
            atomicAdd(&shist[min((int)(v.z * 256.0f), 255)], 1u);
            atomicAdd(&shist[min((int)(v.w * 256.0f), 255)], 1u);
        }
    } else {
        // ----- 3 ballot waves: zero LDS in hot loop (r6-validated) -----
        const unsigned long long t0 = (l & 1)  ? 0ull : ~0ull;
        const unsigned long long t1 = (l & 2)  ? 0ull : ~0ull;
        const unsigned long long t2 = (l & 4)  ? 0ull : ~0ull;
        const unsigned long long t3 = (l & 8)  ? 0ull : ~0ull;
        const unsigned long long t4 = (l & 16) ? 0ull : ~0ull;
        const unsigned long long t5 = (l & 32) ? 0ull : ~0ull;
        unsigned int c0 = 0, c1 = 0, c2 = 0, c3 = 0;  // bins l,l+64,l+128,l+192

        auto grp = [&](float x) {
            int bin = min((int)(x * 256.0f), 255);
            unsigned long long B0 = __ballot(bin & 1);
            unsigned long long B1 = __ballot(bin & 2);
            unsigned long long B2 = __ballot(bin & 4);
            unsigned long long B3 = __ballot(bin & 8);
            unsigned long long B4 = __ballot(bin & 16);
            unsigned long long B5 = __ballot(bin & 32);
            unsigned long long B6 = __ballot(bin & 64);
            unsigned long long B7 = __ballot(bin & 128);
            unsigned long long m = (B0 ^ t0) & (B1 ^ t1) & (B2 ^ t2)
                                 & (B3 ^ t3) & (B4 ^ t4) & (B5 ^ t5);
            unsigned long long a = m & ~B7, b = m & B7;
            c0 += (unsigned)__popcll(a & ~B6);
            c1 += (unsigned)__popcll(a &  B6);
            c2 += (unsigned)__popcll(b & ~B6);
            c3 += (unsigned)__popcll(b &  B6);
        };

        const int ng = SB >> 6;               // 64-float4 groups, lanes all valid
        int g = w - 1;
        if (g < ng) {
            float4 v = p[mid + (g << 6) + l];
            for (; g + 3 < ng; g += 3) {
                float4 nv = p[mid + ((g + 3) << 6) + l];   // 1-deep prefetch
                __builtin_amdgcn_sched_barrier(0);
                grp(v.x); grp(v.y); grp(v.z); grp(v.w);
                v = nv;
            }
            grp(v.x); grp(v.y); grp(v.z); grp(v.w);
        }
        wsum[w - 1][l]       = c0;            // unconditional (may be zeros)
        wsum[w - 1][l + 64]  = c1;
        wsum[w - 1][l + 128] = c2;
        wsum[w - 1][l + 192] = c3;
    }
    __syncthreads();

    part[(((size_t)blockIdx.z * NROWS + y) * CH + blockIdx.x) * BINS + t]
        = shist[t] + wsum[0][t] + wsum[1][t] + wsum[2][t];
}

// ---------------------------------------------------------------------------
// Kernel 2: sum CH per-block partials (exact integers), then the validated
// pipeline: integer Hillis-Steele scan (partials <= 2^20) -> CDF =
// cum/max(total,1e-12) (exact /2^20 -> bit-identical to np's sequential fp32
// cumsum) -> parallelized two-pointer:
//   s_i = searchsorted(cdf_ref, cdf_dst[i]); table[i]=max(1,s_i) before the
//   first failure; first fail poisons all later entries to 255.
// table[0]=0, table[255]=255. lut = table/255. grid = 12 blocks.
// ---------------------------------------------------------------------------
__global__ __launch_bounds__(256) void hm_table(const unsigned int* __restrict__ part,
                                                float* __restrict__ lut) {
    __shared__ unsigned int sd[BINS], sr[BINS];
    __shared__ float cdf_d[BINS], cdf_r[BINS];
    __shared__ int firstFail;

    const int r = blockIdx.x;                 // compact row
    const int t = threadIdx.x;

    const unsigned int* pd = part + ((size_t)0 * NROWS + r) * CH * BINS;
    const unsigned int* pr = part + ((size_t)1 * NROWS + r) * CH * BINS;
    unsigned int xd = 0, xr = 0;
    #pragma unroll 5
    for (int k = 0; k < CH; ++k) {
        xd += pd[k * BINS + t];
        xr += pr[k * BINS + t];
    }
    if (t == 0) firstFail = BINS;
    sd[t] = xd; sr[t] = xr;
    __syncthreads();

    #pragma unroll
    for (int off = 1; off < BINS; off <<= 1) {
        unsigned int yd = (t >= off) ? sd[t - off] : 0u;
        unsigned int yr = (t >= off) ? sr[t - off] : 0u;
        __syncthreads();
        xd += yd; xr += yr;
        sd[t] = xd; sr[t] = xr;
        __syncthreads();
    }
    float totd = fmaxf((float)sd[BINS - 1], 1e-12f);
    float totr = fmaxf((float)sr[BINS - 1], 1e-12f);
    cdf_d[t] = (float)xd / totd;
    cdf_r[t] = (float)xr / totr;
    __syncthreads();

    int out;
    if (t == 0) {
        out = 0;
    } else {
        float d = cdf_d[t];
        int lo = 0, hi = BINS;                // searchsorted 'left' in [0,256]
        while (lo < hi) {
            int m = (lo + hi) >> 1;
            if (cdf_r[m] < d) lo = m + 1; else hi = m;
        }
        int cand = lo > 1 ? lo : 1;
        bool ok = (cand <= BINS - 1) && (d >= cdf_r[cand - 1]);
        if (!ok) atomicMin(&firstFail, t);
        out = cand;
    }
    __syncthreads();

    if (t >= firstFail) out = BINS - 1;
    if (t == BINS - 1) out = BINS - 1;
    lut[(size_t)r * BINS + t] = (float)out / 255.0f;
}

// ---------------------------------------------------------------------------
// Kernel 3 (validated): apply LUT; preserves the reference's row_sel=b*c bug
// via compact mapping. pix = clip(trunc(dst*255),0,255).
// grid = (ACH=128, 24), block = 256, 2-deep load batching.
// ---------------------------------------------------------------------------
__global__ __launch_bounds__(256) void hm_apply(const float* __restrict__ dst,
                                                const float* __restrict__ lut,
                                                float* __restrict__ out,
                                                int n4_per_row) {
    __shared__ float slut[BINS];
    const int bc = blockIdx.y;
    const int b = bc / C_N;
    const int c = bc - b * C_N;
    const int r = b * c;                      // <-- preserved bug
    const int cr = (r <= 8) ? r : 8 + ((r - 8) >> 1);   // compact index
    const int t = threadIdx.x;

    slut[t] = lut[(size_t)cr * BINS + t];
    __syncthreads();

    const float4* in4 = reinterpret_cast<const float4*>(dst) + (size_t)bc * n4_per_row;
    float4* out4 = reinterpret_cast<float4*>(out) + (size_t)bc * n4_per_row;
    const int gsz = gridDim.x * 256;

    int i = blockIdx.x * 256 + t;
    for (; i + gsz < n4_per_row; i += 2 * gsz) {
        float4 v0 = in4[i];
        float4 v1 = in4[i + gsz];
        __builtin_amdgcn_sched_barrier(0);
        float4 o0, o1;
        o0.x = slut[min(max((int)(v0.x * 255.0f), 0), 255)];
        o0.y = slut[min(max((int)(v0.y * 255.0f), 0), 255)];
        o0.z = slut[min(max((int)(v0.z * 255.0f), 0), 255)];
        o0.w = slut[min(max((int)(v0.w * 255.0f), 0), 255)];
        o1.x = slut[min(max((int)(v1.x * 255.0f), 0), 255)];
        o1.y = slut[min(max((int)(v1.y * 255.0f), 0), 255)];
        o1.z = slut[min(max((int)(v1.z * 255.0f), 0), 255)];
        o1.w = slut[min(max((int)(v1.w * 255.0f), 0), 255)];
        out4[i] = o0;
        out4[i + gsz] = o1;
    }
    for (; i < n4_per_row; i += gsz) {
        float4 v = in4[i];
        float4 o;
        o.x = slut[min(max((int)(v.x * 255.0f), 0), 255)];
        o.y = slut[min(max((int)(v.y * 255.0f), 0), 255)];
        o.z = slut[min(max((int)(v.z * 255.0f), 0), 255)];
        o.w = slut[min(max((int)(v.w * 255.0f), 0), 255)];
        out4[i] = o;
    }
}

extern "C" void kernel_launch(void* const* d_in, const int* in_sizes, int n_in,
                              void* d_out, int out_size, void* d_ws, size_t ws_size,
                              hipStream_t stream) {
    const float* dst  = (const float*)d_in[0];
    const float* refp = (const float*)d_in[1];
    float* out = (float*)d_out;

    const int total = in_sizes[0];          // 8*3*1024*1024
    const int hw = total / BC_N;            // 1048576
    const int n4 = hw >> 2;                 // 262144 float4 per row

    // workspace: [part 2 x 12 x 85 x 256 u32 = 2.09 MB][lut 12x256 f32]
    unsigned int* part = (unsigned int*)d_ws;
    float* lut = (float*)((char*)d_ws + (size_t)2 * NROWS * CH * BINS * sizeof(unsigned int));

    dim3 hg(CH, NROWS, 2);
    hm_hist<<<hg, dim3(256), 0, stream>>>(dst, refp, part, n4);

    hm_table<<<dim3(NROWS), dim3(256), 0, stream>>>(part, lut);

    dim3 ag(ACH, BC_N);
    hm_apply<<<ag, dim3(256), 0, stream>>>(dst, lut, out, n4);
}

// Round 15
// 67.838 us; speedup vs baseline: 1.0348x; 1.0348x over previous
//
#include <hip/hip_runtime.h>

#define BINS 256
#define BC_N 24   // B*C = 8*3
#define C_N  3
#define NROWS 12  // the row_sel = b*c bug uses only rows {0..8,10,12,14}
#define CH   85   // hist blocks per (row,img): 85*12*2 = 2040 = ~8/CU
#define ACH  128  // apply chunks

// ---------------------------------------------------------------------------
// Kernel 1 (r13 best-measured config, reverted): 256-bin histograms for the
// 12 USED rows of dst and ref. grid = (CH, 12, 2), block = 256 (4 waves).
//
// Final hardware model (r2-r14): counting is pipe-bound at ~1.1 combined
// lane-ops/cyc/CU. LDS atomic unit: ~1.05 px/cyc/CU, REQUIRES ~24 feeder
// waves/CU (collapses at 8, r14). Ballot bit-slicing: ~0.75 px/cyc/CU on
// VALU. The pipes do NOT sum (shared issue/VALU); best measured mix is
// 3 atomic waves + 1 ballot wave per block at an 81:19 pixel split (r13).
// All alternatives (banking, replication, DMA rings, byte counters, deeper
// MLP, other splits) measured invariant-or-worse across 13 rounds.
// bin = floor(x*256) == trunc for x in [0,1); min-clamp for the 1.0 edge.
// ---------------------------------------------------------------------------
__global__ __launch_bounds__(256) void hm_hist(const float* __restrict__ dst,
                                               const float* __restrict__ refp,
                                               unsigned int* __restrict__ part,
                                               int n4_per_row) {
    __shared__ unsigned int shist[BINS];      // atomic-wave counts
    __shared__ unsigned int wsum[BINS];       // ballot-wave counts

    const int t = threadIdx.x;
    const int l = t & 63;
    const int w = t >> 6;                     // 0..3

    shist[t] = 0u;
    __syncthreads();

    const int y = blockIdx.y;
    const int row = (y < 9) ? y : 2 * y - 8;  // {0..8,10,12,14}
    const float* img = blockIdx.z ? refp : dst;
    const float4* p = reinterpret_cast<const float4*>(img) + (size_t)row * n4_per_row;

    const int span = (n4_per_row + CH - 1) / CH;         // 3085
    const int lo = blockIdx.x * span;
    const int hi = min(lo + span, n4_per_row);
    const int n  = hi - lo;
    const int SB = ((n * 19) / 100) & ~63;    // ballot segment: multiple of 64
    const int mid = hi - SB;                  // [lo,mid) atomic, [mid,hi) ballot

    if (w < 3) {
        // ----- 3 atomic-feeder waves: grid-stride 192 lanes, fire-and-forget -----
        for (int i = lo + w * 64 + l; i < mid; i += 192) {
            float4 v = p[i];
            atomicAdd(&shist[min((int)(v.x * 256.0f), 255)], 1u);
            atomicAdd(&shist[min((int)(v.y * 256.0f), 255)], 1u);
            atomicAdd(&shist[min((int)(v.z * 256.0f), 255)], 1u);
            atomicAdd(&shist[min((int)(v.w * 256.0f), 255)], 1u);
        }
    } else {
        // ----- 1 ballot wave: zero LDS in hot loop (r6-validated) -----
        const unsigned long long t0 = (l & 1)  ? 0ull : ~0ull;
        const unsigned long long t1 = (l & 2)  ? 0ull : ~0ull;
        const unsigned long long t2 = (l & 4)  ? 0ull : ~0ull;
        const unsigned long long t3 = (l & 8)  ? 0ull : ~0ull;
        const unsigned long long t4 = (l & 16) ? 0ull : ~0ull;
        const unsigned long long t5 = (l & 32) ? 0ull : ~0ull;
        unsigned int c0 = 0, c1 = 0, c2 = 0, c3 = 0;  // bins l,l+64,l+128,l+192

        auto grp = [&](float x) {
            int bin = min((int)(x * 256.0f), 255);
            unsigned long long B0 = __ballot(bin & 1);
            unsigned long long B1 = __ballot(bin & 2);
            unsigned long long B2 = __ballot(bin & 4);
            unsigned long long B3 = __ballot(bin & 8);
            unsigned long long B4 = __ballot(bin & 16);
            unsigned long long B5 = __ballot(bin & 32);
            unsigned long long B6 = __ballot(bin & 64);
            unsigned long long B7 = __ballot(bin & 128);
            unsigned long long m = (B0 ^ t0) & (B1 ^ t1) & (B2 ^ t2)
                                 & (B3 ^ t3) & (B4 ^ t4) & (B5 ^ t5);
            unsigned long long a = m & ~B7, b = m & B7;
            c0 += (unsigned)__popcll(a & ~B6);
            c1 += (unsigned)__popcll(a &  B6);
            c2 += (unsigned)__popcll(b & ~B6);
            c3 += (unsigned)__popcll(b &  B6);
        };

        const int nk = SB >> 6;               // 64-float4 groups, all lanes valid
        if (nk > 0) {
            float4 v = p[mid + l];
            for (int k = 0; k + 1 < nk; ++k) {
                float4 nv = p[mid + ((k + 1) << 6) + l];   // 1-deep prefetch
                __builtin_amdgcn_sched_barrier(0);
                grp(v.x); grp(v.y); grp(v.z); grp(v.w);
                v = nv;
            }
            grp(v.x); grp(v.y); grp(v.z); grp(v.w);
        }
        wsum[l]       = c0;                   // unconditional (c's may be 0)
        wsum[l + 64]  = c1;
        wsum[l + 128] = c2;
        wsum[l + 192] = c3;
    }
    __syncthreads();

    part[(((size_t)blockIdx.z * NROWS + y) * CH + blockIdx.x) * BINS + t]
        = shist[t] + wsum[t];
}

// ---------------------------------------------------------------------------
// Kernel 2: sum CH per-block partials (exact integers), then the validated
// pipeline: integer Hillis-Steele scan (partials <= 2^20) -> CDF =
// cum/max(total,1e-12) (exact /2^20 -> bit-identical to np's sequential fp32
// cumsum) -> parallelized two-pointer:
//   s_i = searchsorted(cdf_ref, cdf_dst[i]); table[i]=max(1,s_i) before the
//   first failure; first fail poisons all later entries to 255.
// table[0]=0, table[255]=255. lut = table/255. grid = 12 blocks.
// ---------------------------------------------------------------------------
__global__ __launch_bounds__(256) void hm_table(const unsigned int* __restrict__ part,
                                                float* __restrict__ lut) {
    __shared__ unsigned int sd[BINS], sr[BINS];
    __shared__ float cdf_d[BINS], cdf_r[BINS];
    __shared__ int firstFail;

    const int r = blockIdx.x;                 // compact row
    const int t = threadIdx.x;

    const unsigned int* pd = part + ((size_t)0 * NROWS + r) * CH * BINS;
    const unsigned int* pr = part + ((size_t)1 * NROWS + r) * CH * BINS;
    unsigned int xd = 0, xr = 0;
    #pragma unroll 5
    for (int k = 0; k < CH; ++k) {
        xd += pd[k * BINS + t];
        xr += pr[k * BINS + t];
    }
    if (t == 0) firstFail = BINS;
    sd[t] = xd; sr[t] = xr;
    __syncthreads();

    #pragma unroll
    for (int off = 1; off < BINS; off <<= 1) {
        unsigned int yd = (t >= off) ? sd[t - off] : 0u;
        unsigned int yr = (t >= off) ? sr[t - off] : 0u;
        __syncthreads();
        xd += yd; xr += yr;
        sd[t] = xd; sr[t] = xr;
        __syncthreads();
    }
    float totd = fmaxf((float)sd[BINS - 1], 1e-12f);
    float totr = fmaxf((float)sr[BINS - 1], 1e-12f);
    cdf_d[t] = (float)xd / totd;
    cdf_r[t] = (float)xr / totr;
    __syncthreads();

    int out;
    if (t == 0) {
        out = 0;
    } else {
        float d = cdf_d[t];
        int lo = 0, hi = BINS;                // searchsorted 'left' in [0,256]
        while (lo < hi) {
            int m = (lo + hi) >> 1;
            if (cdf_r[m] < d) lo = m + 1; else hi = m;
        }
        int cand = lo > 1 ? lo : 1;
        bool ok = (cand <= BINS - 1) && (d >= cdf_r[cand - 1]);
        if (!ok) atomicMin(&firstFail, t);
        out = cand;
    }
    __syncthreads();

    if (t >= firstFail) out = BINS - 1;
    if (t == BINS - 1) out = BINS - 1;
    lut[(size_t)r * BINS + t] = (float)out / 255.0f;
}

// ---------------------------------------------------------------------------
// Kernel 3 (validated): apply LUT; preserves the reference's row_sel=b*c bug
// via compact mapping. pix = clip(trunc(dst*255),0,255).
// grid = (ACH=128, 24), block = 256, 2-deep load batching.
// ---------------------------------------------------------------------------
__global__ __launch_bounds__(256) void hm_apply(const float* __restrict__ dst,
                                                const float* __restrict__ lut,
                                                float* __restrict__ out,
                                                int n4_per_row) {
    __shared__ float slut[BINS];
    const int bc = blockIdx.y;
    const int b = bc / C_N;
    const int c = bc - b * C_N;
    const int r = b * c;                      // <-- preserved bug
    const int cr = (r <= 8) ? r : 8 + ((r - 8) >> 1);   // compact index
    const int t = threadIdx.x;

    slut[t] = lut[(size_t)cr * BINS + t];
    __syncthreads();

    const float4* in4 = reinterpret_cast<const float4*>(dst) + (size_t)bc * n4_per_row;
    float4* out4 = reinterpret_cast<float4*>(out) + (size_t)bc * n4_per_row;
    const int gsz = gridDim.x * 256;

    int i = blockIdx.x * 256 + t;
    for (; i + gsz < n4_per_row; i += 2 * gsz) {
        float4 v0 = in4[i];
        float4 v1 = in4[i + gsz];
        __builtin_amdgcn_sched_barrier(0);
        float4 o0, o1;
        o0.x = slut[min(max((int)(v0.x * 255.0f), 0), 255)];
        o0.y = slut[min(max((int)(v0.y * 255.0f), 0), 255)];
        o0.z = slut[min(max((int)(v0.z * 255.0f), 0), 255)];
        o0.w = slut[min(max((int)(v0.w * 255.0f), 0), 255)];
        o1.x = slut[min(max((int)(v1.x * 255.0f), 0), 255)];
        o1.y = slut[min(max((int)(v1.y * 255.0f), 0), 255)];
        o1.z = slut[min(max((int)(v1.z * 255.0f), 0), 255)];
        o1.w = slut[min(max((int)(v1.w * 255.0f), 0), 255)];
        out4[i] = o0;
        out4[i + gsz] = o1;
    }
    for (; i < n4_per_row; i += gsz) {
        float4 v = in4[i];
        float4 o;
        o.x = slut[min(max((int)(v.x * 255.0f), 0), 255)];
        o.y = slut[min(max((int)(v.y * 255.0f), 0), 255)];
        o.z = slut[min(max((int)(v.z * 255.0f), 0), 255)];
        o.w = slut[min(max((int)(v.w * 255.0f), 0), 255)];
        out4[i] = o;
    }
}

extern "C" void kernel_launch(void* const* d_in, const int* in_sizes, int n_in,
                              void* d_out, int out_size, void* d_ws, size_t ws_size,
                              hipStream_t stream) {
    const float* dst  = (const float*)d_in[0];
    const float* refp = (const float*)d_in[1];
    float* out = (float*)d_out;

    const int total = in_sizes[0];          // 8*3*1024*1024
    const int hw = total / BC_N;            // 1048576
    const int n4 = hw >> 2;                 // 262144 float4 per row

    // workspace: [part 2 x 12 x 85 x 256 u32 = 2.09 MB][lut 12x256 f32]
    unsigned int* part = (unsigned int*)d_ws;
    float* lut = (float*)((char*)d_ws + (size_t)2 * NROWS * CH * BINS * sizeof(unsigned int));

    dim3 hg(CH, NROWS, 2);
    hm_hist<<<hg, dim3(256), 0, stream>>>(dst, refp, part, n4);

    hm_table<<<dim3(NROWS), dim3(256), 0, stream>>>(part, lut);

    dim3 ag(ACH, BC_N);
    hm_apply<<<ag, dim3(256), 0, stream>>>(dst, lut, out, n4);
}